// Round 6
// baseline (752.677 us; speedup 1.0000x reference)
//
#include <hip/hip_runtime.h>
#include <hip/hip_bf16.h>
#include <math.h>

// Problem constants (fixed by setup_inputs)
#define B_ 2
#define N_ 4096
#define D_ 2048
#define H_ 16
#define DH_ 128
#define CHUNK_ 256
#define NC_ 16
#define M_ (B_*N_)          // 8192 tokens
#define F3D (3*D_)          // 6144

typedef __bf16 v8bf __attribute__((ext_vector_type(8)));
typedef float  v4f  __attribute__((ext_vector_type(4)));
typedef unsigned short u16x8 __attribute__((ext_vector_type(8)));

__device__ __forceinline__ float bf2f(unsigned short u) {
    union { unsigned int i; float f; } c; c.i = ((unsigned int)u) << 16; return c.f;
}
__device__ __forceinline__ unsigned short f2bf(float f) {
    __hip_bfloat16 h = __float2bfloat16(f);
    return *(unsigned short*)&h;
}

__device__ __forceinline__ void async_copy16(void* lds, const void* g) {
    __builtin_amdgcn_global_load_lds(
        (const __attribute__((address_space(1))) unsigned int*)g,
        (__attribute__((address_space(3))) unsigned int*)lds,
        16, 0, 0);
}

// ---------------- RMSNorm: x (f32) -> xn (bf16), 8 elems/thread ----------------
__global__ __launch_bounds__(256) void k_rmsnorm(const float* __restrict__ x,
                                                 const float* __restrict__ scale,
                                                 __hip_bfloat16* __restrict__ xn)
{
    __shared__ float red[4];
    const int row = blockIdx.x;
    const float4* x4 = (const float4*)(x + (size_t)row * D_);
    float4 a = x4[threadIdx.x*2];
    float4 b = x4[threadIdx.x*2 + 1];
    float ss = a.x*a.x + a.y*a.y + a.z*a.z + a.w*a.w
             + b.x*b.x + b.y*b.y + b.z*b.z + b.w*b.w;
    #pragma unroll
    for (int off = 32; off > 0; off >>= 1) ss += __shfl_down(ss, off, 64);
    if ((threadIdx.x & 63) == 0) red[threadIdx.x >> 6] = ss;
    __syncthreads();
    float tot = red[0] + red[1] + red[2] + red[3];
    float r = rsqrtf(tot / (float)D_ + 1e-6f);
    const float4* s4 = (const float4*)scale;
    float4 sa = s4[threadIdx.x*2];
    float4 sb = s4[threadIdx.x*2 + 1];
    float v[8] = { sa.x*a.x, sa.y*a.y, sa.z*a.z, sa.w*a.w,
                   sb.x*b.x, sb.y*b.y, sb.z*b.z, sb.w*b.w };
    u16x8 o;
    #pragma unroll
    for (int j = 0; j < 8; ++j) {
        float t = fminf(fmaxf(v[j]*r, -60000.f), 60000.f);
        o[j] = f2bf(t);
    }
    ((u16x8*)(xn + (size_t)row * D_))[threadIdx.x] = o;
}

// ---------------- depthwise causal conv (K=4) + SiLU, 8 elems/thread ----------------
__global__ __launch_bounds__(256) void k_conv_silu(const __hip_bfloat16* __restrict__ xn,
                                                   const float* __restrict__ w,
                                                   const float* __restrict__ bias,
                                                   __hip_bfloat16* __restrict__ xc)
{
    size_t p = (size_t)blockIdx.x * 256 + threadIdx.x;  // over M*D/8
    size_t e0 = p * 8;
    int d0 = (int)(e0 & (D_-1));
    int n  = (int)((e0 >> 11) & (N_-1));
    const float4* w4 = (const float4*)w;               // w4[d] = weights of channel d
    float acc[8];
    const float4* b4 = (const float4*)(bias + d0);
    float4 ba = b4[0], bb = b4[1];
    acc[0]=ba.x; acc[1]=ba.y; acc[2]=ba.z; acc[3]=ba.w;
    acc[4]=bb.x; acc[5]=bb.y; acc[6]=bb.z; acc[7]=bb.w;
    float4 wv[8];
    #pragma unroll
    for (int j = 0; j < 8; ++j) wv[j] = w4[d0 + j];
    #pragma unroll
    for (int k = 0; k < 4; ++k) {
        int nn = n - 3 + k;
        if (nn >= 0) {
            u16x8 t = *(const u16x8*)(xn + e0 - (size_t)(3-k)*D_);
            #pragma unroll
            for (int j = 0; j < 8; ++j) {
                float wk = (k==0)?wv[j].x:(k==1)?wv[j].y:(k==2)?wv[j].z:wv[j].w;
                acc[j] += bf2f(t[j]) * wk;
            }
        }
    }
    u16x8 o;
    #pragma unroll
    for (int j = 0; j < 8; ++j) {
        float s = acc[j] / (1.f + __expf(-acc[j]));
        o[j] = f2bf(s);
    }
    *(u16x8*)(xc + e0) = o;
}

// ---------------- f32 -> bf16 cast (weights), 8 elems/thread ----------------
__global__ __launch_bounds__(256) void k_cast_bf16(const float* __restrict__ src,
                                                   __hip_bfloat16* __restrict__ dst)
{
    size_t p = (size_t)blockIdx.x * 256 + threadIdx.x;
    const float4* s4 = (const float4*)src;
    float4 a = s4[p*2], b = s4[p*2 + 1];
    u16x8 o;
    o[0]=f2bf(a.x); o[1]=f2bf(a.y); o[2]=f2bf(a.z); o[3]=f2bf(a.w);
    o[4]=f2bf(b.x); o[5]=f2bf(b.y); o[6]=f2bf(b.z); o[7]=f2bf(b.w);
    ((u16x8*)dst)[p] = o;
}

// ---------------- bf16 NT GEMM: acc[m][n] = sum_k A[m][k] * W[n][k] ----------------
// Round-6: 128x128 tile, BK=32, 4 waves (2x2 of 64x64), 3-buffer depth-2 free-run
// pipeline (round-3 scheme, verified), LDS = 3 x (A 8KB + B 8KB) = 48 KiB ->
// 3 blocks/CU (m97-style occupancy: cross-block MFMA||LDS||stage overlap, m114).
// Packed-pair conflict-free LDS layout: global (m, kg: 8-elem k-group 0..3) stored
// at LDS row r=m>>1 (128 B rows), slot s = ((m&1)*4+kg) ^ (r&7). Wave read
// (fr=lane&15, qk=lane>>4): slot residues hit every bank-pair exactly 2x -> free
// (m136: 2-way is free). Stage: linear gload_lds dest (wave-uniform base+lane*16),
// per-lane pre-swizzled global source (rule #21).
// Ledger (2 loads per stage(T,x) call per thread): prologue stages tiles 0,1 (8
// outstanding); top of tile t waits vmcnt(4) (retires tile t), stages tile t+2
// into buf (t+2)%3 = (t-1)%3 (reads closed by the barrier). Last tile: vmcnt(0).
// T1 XCD-bijective swizzle; T5 setprio around MFMA cluster.
// MODE 0: in_proj — stream 0: la = -clip(softplus(acc+dt_bias[n]),0.001,2) (f32)
//                   stream 1: v raw (bf16);  stream 2: sigmoid -> gate (bf16)
// MODE 1: out_proj — out[off] = acc + resid[off]  (f32)
template<int MODE>
__global__ __launch_bounds__(256, 3) void k_gemm(const __hip_bfloat16* __restrict__ Abf,
                                              const __hip_bfloat16* __restrict__ Wbf,
                                              int K,
                                              float* __restrict__ o0,
                                              __hip_bfloat16* __restrict__ o1,
                                              __hip_bfloat16* __restrict__ o2,
                                              const float* __restrict__ dt_bias,
                                              const float* __restrict__ resid,
                                              float* __restrict__ outp)
{
    // [buf 0..2][A=0/B=1][64 rows x 128 B = 8 KiB]
    __shared__ __attribute__((aligned(16))) char lds[3][2][8192];
    const __bf16* A = (const __bf16*)Abf;
    const __bf16* W = (const __bf16*)Wbf;
    const int tid  = threadIdx.x;
    const int wave = tid >> 6;
    const int lane = tid & 63;

    // T1: bijective XCD swizzle over linearized grid (nwg % 8 == 0 for all call sites)
    const int gx  = gridDim.x;
    int bid = blockIdx.y * gx + blockIdx.x;
    int cpx = (gx * gridDim.y) >> 3;
    int swzb = (bid & 7) * cpx + (bid >> 3);
    int bx = swzb % gx, by = swzb / gx;

    const size_t m0 = (size_t)bx * 128;
    const size_t n0 = (size_t)by * 128;
    const int wm = (wave & 1) * 64;
    const int wn = (wave >> 1) * 64;

    v4f acc[4][4] = {};

    const int fr = lane & 15;             // fragment row within 16
    const int qk = lane >> 4;             // 8-elem k-group 0..3
    const int srL = lane >> 3;            // stage: row within 8-row lane slab
    const int ssL = lane & 7;             // stage: slot

    const int nt = K >> 5;                // BK=32

    // stage tile T (A or B, full 128 rows x 32 cols) into buf[T%3]; 2 issues/thread
    auto stage = [&](int T, int isB) {
        char* reg = &lds[T % 3][isB][0];
        const __bf16* gp = (isB ? W + n0 * (size_t)K : A + m0 * (size_t)K);
        #pragma unroll
        for (int is = 0; is < 2; ++is) {
            int r  = is*32 + wave*8 + srL;          // LDS row 0..63
            int u  = ssL ^ (r & 7);                 // unswizzled slot
            int m  = 2*r + (u >> 2);                // global row 0..127
            int kg = u & 3;
            const __bf16* src = gp + (size_t)m * K + (T << 5) + kg*8;
            async_copy16((void*)(reg + is*4096 + wave*1024), (const void*)src);
        }
    };
    // read 4 fragments (rows wbase + i*16 + fr, k-group qk)
    auto rd = [&](v8bf* f, const char* reg, int wbase) {
        #pragma unroll
        for (int i = 0; i < 4; ++i) {
            int m = wbase + i*16 + fr;
            int r = m >> 1;
            int s = (((m & 1) << 2) | qk) ^ (r & 7);
            f[i] = *(const v8bf*)(reg + r*128 + s*16);
        }
    };

    // prologue: tiles 0 and 1 -> 8 outstanding/thread
    stage(0, 0); stage(0, 1);
    stage(1, 0); stage(1, 1);

    for (int t = 0; t < nt; ++t) {
        if (t + 1 < nt) { asm volatile("s_waitcnt vmcnt(4)" ::: "memory"); }
        else            { asm volatile("s_waitcnt vmcnt(0)" ::: "memory"); }
        __builtin_amdgcn_s_barrier();      // tile t visible; reads of buf (t-1)%3 closed
        __builtin_amdgcn_sched_barrier(0);

        const char* Ab = &lds[t % 3][0][0];
        const char* Bb = &lds[t % 3][1][0];

        if (t + 2 < nt) { stage(t + 2, 0); stage(t + 2, 1); }

        v8bf fa[4], fb[4];
        rd(fa, Ab, wm);
        rd(fb, Bb, wn);

        __builtin_amdgcn_s_setprio(1);
        #pragma unroll
        for (int i = 0; i < 4; ++i)
            #pragma unroll
            for (int j = 0; j < 4; ++j)
                acc[i][j] = __builtin_amdgcn_mfma_f32_16x16x32_bf16(fa[i], fb[j], acc[i][j], 0, 0, 0);
        __builtin_amdgcn_s_setprio(0);
    }

    // epilogue: C/D layout col=lane&15, row=(lane>>4)*4+r  (m89-verified)
    const int col = lane & 15;
    const int rb  = (lane >> 4) * 4;
    if (MODE == 0) {
        const int stream = by >> 4;                 // 2048/128 = 16 blocks/stream
        const size_t nb = n0 - (size_t)stream * D_;
        #pragma unroll
        for (int i = 0; i < 4; ++i)
            #pragma unroll
            for (int j = 0; j < 4; ++j) {
                size_t nIdx = nb + wn + j*16 + col;
                #pragma unroll
                for (int r = 0; r < 4; ++r) {
                    size_t m = m0 + wm + i*16 + rb + r;
                    size_t off = m * (size_t)D_ + nIdx;
                    float v = acc[i][j][r];
                    if (stream == 0) {
                        float xx = v + dt_bias[nIdx];
                        float e  = __expf(-fabsf(xx));
                        float sp = fmaxf(xx, 0.f) + __logf(1.f + e);
                        float dt = fminf(fmaxf(sp, 0.001f), 2.0f);
                        o0[off] = -dt;                                    // log_alpha
                    } else if (stream == 1) {
                        o1[off] = __float2bfloat16(v);                    // raw v
                    } else {
                        o2[off] = __float2bfloat16(1.f/(1.f+__expf(-v))); // gate
                    }
                }
            }
    } else {
        #pragma unroll
        for (int i = 0; i < 4; ++i)
            #pragma unroll
            for (int j = 0; j < 4; ++j)
                #pragma unroll
                for (int r = 0; r < 4; ++r) {
                    size_t m = m0 + wm + i*16 + rb + r;
                    size_t off = m * (size_t)D_ + n0 + wn + j*16 + col;
                    outp[off] = acc[i][j][r] + resid[off];
                }
    }
}

// ---------------- scan phase 1: RoPE*dt fused; writes bd, bo, nc (f32), expL (bf16) ----
// nc[off]  = chunk-local scan output (pre-carry), f32.
// expL[off]= exp(L_t), bf16 (only scales the decaying carry term -> 0.4% rel ok).
__global__ __launch_bounds__(256) void k_scan1(const float* __restrict__ la,
                                               const __hip_bfloat16* __restrict__ v,
                                               float* __restrict__ bd, float* __restrict__ bo,
                                               float* __restrict__ nc,
                                               __hip_bfloat16* __restrict__ expL)
{
    int idx = blockIdx.x * 256 + threadIdx.x;   // B*NC*D = 65536
    int d = idx & (D_-1);
    int c = (idx >> 11) & (NC_-1);
    int b = idx >> 15;
    int i = d & 63;
    const bool firstHalf = (d & 64) == 0;
    float inv = __expf((float)i * (-9.210340371976184f / 64.f)); // 10000^(-i/64)
    int n0 = c * CHUNK_;
    // incremental rotation: (cs,sn) = (cos,sin)(n*inv), step by inv
    float cs = cosf((float)n0 * inv), sn = sinf((float)n0 * inv);
    float ca = cosf(inv), sa = sinf(inv);
    size_t row0 = (size_t)b * N_ + (size_t)c * CHUNK_;
    float S = 0.f, Lp = 0.f, out = 0.f;
    #pragma unroll 8
    for (int t = 0; t < CHUNK_; ++t) {
        size_t off = (row0 + t) * (size_t)D_ + d;
        float a  = la[off];
        float vo = __bfloat162float(v[off]);
        float vp = __bfloat162float(v[firstHalf ? off + 64 : off - 64]);
        float dt = -a;
        float vin = (firstHalf ? (vo*cs - vp*sn) : (vp*sn + vo*cs)) * dt;
        S += a;
        float L = fmaxf(S, -20.f);           // clip(cumsum,-20,0): upper never binds
        out = __expf(L - Lp) * out + vin;
        Lp = L;
        nc[off]   = out;
        expL[off] = __float2bfloat16(__expf(L));
        float csn = cs*ca - sn*sa;           // advance angle by inv
        sn = sn*ca + cs*sa;
        cs = csn;
    }
    bd[idx] = Lp;
    bo[idx] = out;
}

// ---------------- scan phase 2: cross-chunk combine -> carries ----------------
__global__ __launch_bounds__(256) void k_scan2(const float* __restrict__ bd,
                                               const float* __restrict__ bo,
                                               float* __restrict__ carries)
{
    int idx = blockIdx.x * 256 + threadIdx.x;   // B*D = 4096
    int d = idx & (D_-1);
    int b = idx >> 11;
    float bd0 = bd[(size_t)(b*NC_)*D_ + d];     // stab = cd[0] = bd[0] (>= -20)
    float cd = 0.f, acc = 0.f;
    #pragma unroll
    for (int c = 0; c < NC_; ++c) {
        size_t o = (size_t)(b*NC_ + c)*D_ + d;
        cd = fmaxf(cd + bd[o], -80.f);          // clip(cumsum(bd),-80,0)
        float ncd = fmaxf(cd - bd0, -20.f);     // clip(cd-stab,-20,0)
        carries[o] = acc * __expf(ncd);         // sum of seeds STRICTLY BEFORE c
        acc += bo[o] * __expf(-ncd);
    }
}

// ---------------- scan fixup (replaces serial scan3): elementwise, in-place over expL ----
// state[off] = bf16( nc[off] + carr[b,c,d] * expL[off] );  stex holds expL in, state out.
__global__ __launch_bounds__(256) void k_scanfix(const float* __restrict__ nc,
                                                 __hip_bfloat16* __restrict__ stex,
                                                 const float* __restrict__ carr)
{
    size_t idx = (size_t)blockIdx.x * 256 + threadIdx.x;   // over M*D/8
    size_t e0 = idx * 8;
    int d0 = (int)(e0 & (D_-1));
    int token = (int)(e0 >> 11);
    int b = token >> 12;                 // N_=4096
    int c = (token & (N_-1)) >> 8;       // CHUNK_=256
    const float* cp = carr + ((size_t)(b*NC_ + c)) * D_ + d0;
    u16x8 el = ((const u16x8*)stex)[idx];
    const float4* n4 = (const float4*)(nc + e0);
    float4 na = n4[0], nb = n4[1];
    const float4* c4 = (const float4*)cp;
    float4 ca = c4[0], cb = c4[1];
    float nv[8] = { na.x, na.y, na.z, na.w, nb.x, nb.y, nb.z, nb.w };
    float cv[8] = { ca.x, ca.y, ca.z, ca.w, cb.x, cb.y, cb.z, cb.w };
    u16x8 o;
    #pragma unroll
    for (int j = 0; j < 8; ++j)
        o[j] = f2bf(nv[j] + cv[j] * bf2f(el[j]));
    ((u16x8*)stex)[idx] = o;
}

// ---------------- head_mix (generic 16x16) * gate -> y (bf16) ----------------
__global__ __launch_bounds__(256) void k_headmix_gate(const __hip_bfloat16* __restrict__ state,
                                                      const __hip_bfloat16* __restrict__ gate,
                                                      const float* __restrict__ hm,
                                                      __hip_bfloat16* __restrict__ y)
{
    __shared__ float lf[D_];
    __shared__ float lhm[H_*H_];
    const int row = blockIdx.x;
    const size_t base = (size_t)row * D_;
    u16x8 s8 = ((const u16x8*)(state + base))[threadIdx.x];
    #pragma unroll
    for (int j = 0; j < 8; ++j) lf[threadIdx.x*8 + j] = bf2f(s8[j]);
    if (threadIdx.x < H_*H_) lhm[threadIdx.x] = hm[threadIdx.x];
    __syncthreads();
    #pragma unroll
    for (int k = 0; k < 8; ++k) {
        int o = threadIdx.x + k*256;
        int m  = o >> 7;
        int dh = o & 127;
        float s = 0.f;
        #pragma unroll
        for (int h = 0; h < H_; ++h) s += lf[h*DH_ + dh] * lhm[h*H_ + m];
        float g = __bfloat162float(gate[base + o]);
        y[base + o] = __float2bfloat16(s * g);
    }
}

extern "C" void kernel_launch(void* const* d_in, const int* in_sizes, int n_in,
                              void* d_out, int out_size, void* d_ws, size_t ws_size,
                              hipStream_t stream)
{
    const float* x          = (const float*)d_in[0];
    const float* norm_scale = (const float*)d_in[1];
    const float* conv_w     = (const float*)d_in[2];
    const float* conv_b     = (const float*)d_in[3];
    const float* in_proj_w  = (const float*)d_in[4];
    const float* dt_bias    = (const float*)d_in[5];
    const float* head_mix   = (const float*)d_in[6];
    const float* out_proj_w = (const float*)d_in[7];
    float* out = (float*)d_out;

    // Workspace layout — total 176,947,200 B.
    char* ws = (char*)d_ws;
    float*          la   = (float*)ws;                               // 67,108,864 B (log_alpha, f32)
    __hip_bfloat16* xn   = (__hip_bfloat16*)(ws + 67108864);         // 33,554,432 B; -> w1 after conv
    __hip_bfloat16* xc   = (__hip_bfloat16*)(ws + 100663296);        // 33,554,432 B; -> y after scanfix
    __hip_bfloat16* gate = (__hip_bfloat16*)(ws + 134217728);        // 33,554,432 B
    __hip_bfloat16* w2   = (__hip_bfloat16*)(ws + 167772160);        //  8,388,608 B
    float*          bd   = (float*)(ws + 176160768);                 //    262,144 B
    float*          bo   = (float*)(ws + 176422912);                 //    262,144 B
    float*          carr = (float*)(ws + 176685056);                 //    262,144 B
    __hip_bfloat16* w1   = xn;   // xn dead after conv
    // nc (f32, M*D = 67 MB) spans xn+xc — both dead during the scan (w1 consumed by
    // GEMM1, xc consumed by GEMM1); y (=xc) is written by headmix AFTER nc is dead.
    float*          nc   = (float*)(ws + 67108864);
    __hip_bfloat16* y    = xc;
    // d_out scratch: v (bf16, first half); stex (second half) holds expL then state
    // (scanfix is elementwise in-place), all dead before GEMM2 writes the final out.
    __hip_bfloat16* v     = (__hip_bfloat16*)d_out;
    __hip_bfloat16* stex  = (__hip_bfloat16*)((char*)d_out + 33554432);

    k_rmsnorm<<<M_, 256, 0, stream>>>(x, norm_scale, xn);
    k_conv_silu<<<(M_*(size_t)D_)/8/256, 256, 0, stream>>>(xn, conv_w, conv_b, xc);
    k_cast_bf16<<<6144, 256, 0, stream>>>(in_proj_w, w1);
    k_cast_bf16<<<2048, 256, 0, stream>>>(out_proj_w, w2);
    k_gemm<0><<<dim3(M_/128, F3D/128), 256, 0, stream>>>(xc, w1, D_, la, v, gate, dt_bias, nullptr, nullptr);
    k_scan1<<<(B_*NC_*D_)/256, 256, 0, stream>>>(la, v, bd, bo, nc, stex);
    k_scan2<<<(B_*D_)/256, 256, 0, stream>>>(bd, bo, carr);
    k_scanfix<<<(M_*(size_t)D_)/8/256, 256, 0, stream>>>(nc, stex, carr);
    k_headmix_gate<<<M_, 256, 0, stream>>>(stex, gate, head_mix, y);
    k_gemm<1><<<dim3(M_/128, D_/128), 256, 0, stream>>>(y, w2, D_, nullptr, nullptr, nullptr, nullptr, x, out);
}

// Round 7
// 688.319 us; speedup vs baseline: 1.0935x; 1.0935x over previous
//
#include <hip/hip_runtime.h>
#include <hip/hip_bf16.h>
#include <math.h>

// Problem constants (fixed by setup_inputs)
#define B_ 2
#define N_ 4096
#define D_ 2048
#define H_ 16
#define DH_ 128
#define CHUNK_ 256
#define NC_ 16
#define M_ (B_*N_)          // 8192 tokens
#define F3D (3*D_)          // 6144

typedef __bf16 v8bf __attribute__((ext_vector_type(8)));
typedef float  v4f  __attribute__((ext_vector_type(4)));
typedef unsigned short u16x8 __attribute__((ext_vector_type(8)));

__device__ __forceinline__ float bf2f(unsigned short u) {
    union { unsigned int i; float f; } c; c.i = ((unsigned int)u) << 16; return c.f;
}
__device__ __forceinline__ unsigned short f2bf(float f) {
    __hip_bfloat16 h = __float2bfloat16(f);
    return *(unsigned short*)&h;
}

__device__ __forceinline__ void async_copy16(void* lds, const void* g) {
    __builtin_amdgcn_global_load_lds(
        (const __attribute__((address_space(1))) unsigned int*)g,
        (__attribute__((address_space(3))) unsigned int*)lds,
        16, 0, 0);
}

// ---------------- RMSNorm: x (f32) -> xn (bf16), 8 elems/thread ----------------
__global__ __launch_bounds__(256) void k_rmsnorm(const float* __restrict__ x,
                                                 const float* __restrict__ scale,
                                                 __hip_bfloat16* __restrict__ xn)
{
    __shared__ float red[4];
    const int row = blockIdx.x;
    const float4* x4 = (const float4*)(x + (size_t)row * D_);
    float4 a = x4[threadIdx.x*2];
    float4 b = x4[threadIdx.x*2 + 1];
    float ss = a.x*a.x + a.y*a.y + a.z*a.z + a.w*a.w
             + b.x*b.x + b.y*b.y + b.z*b.z + b.w*b.w;
    #pragma unroll
    for (int off = 32; off > 0; off >>= 1) ss += __shfl_down(ss, off, 64);
    if ((threadIdx.x & 63) == 0) red[threadIdx.x >> 6] = ss;
    __syncthreads();
    float tot = red[0] + red[1] + red[2] + red[3];
    float r = rsqrtf(tot / (float)D_ + 1e-6f);
    const float4* s4 = (const float4*)scale;
    float4 sa = s4[threadIdx.x*2];
    float4 sb = s4[threadIdx.x*2 + 1];
    float v[8] = { sa.x*a.x, sa.y*a.y, sa.z*a.z, sa.w*a.w,
                   sb.x*b.x, sb.y*b.y, sb.z*b.z, sb.w*b.w };
    u16x8 o;
    #pragma unroll
    for (int j = 0; j < 8; ++j) {
        float t = fminf(fmaxf(v[j]*r, -60000.f), 60000.f);
        o[j] = f2bf(t);
    }
    ((u16x8*)(xn + (size_t)row * D_))[threadIdx.x] = o;
}

// ---------------- depthwise causal conv (K=4) + SiLU, 8 elems/thread ----------------
__global__ __launch_bounds__(256) void k_conv_silu(const __hip_bfloat16* __restrict__ xn,
                                                   const float* __restrict__ w,
                                                   const float* __restrict__ bias,
                                                   __hip_bfloat16* __restrict__ xc)
{
    size_t p = (size_t)blockIdx.x * 256 + threadIdx.x;  // over M*D/8
    size_t e0 = p * 8;
    int d0 = (int)(e0 & (D_-1));
    int n  = (int)((e0 >> 11) & (N_-1));
    const float4* w4 = (const float4*)w;               // w4[d] = weights of channel d
    float acc[8];
    const float4* b4 = (const float4*)(bias + d0);
    float4 ba = b4[0], bb = b4[1];
    acc[0]=ba.x; acc[1]=ba.y; acc[2]=ba.z; acc[3]=ba.w;
    acc[4]=bb.x; acc[5]=bb.y; acc[6]=bb.z; acc[7]=bb.w;
    float4 wv[8];
    #pragma unroll
    for (int j = 0; j < 8; ++j) wv[j] = w4[d0 + j];
    #pragma unroll
    for (int k = 0; k < 4; ++k) {
        int nn = n - 3 + k;
        if (nn >= 0) {
            u16x8 t = *(const u16x8*)(xn + e0 - (size_t)(3-k)*D_);
            #pragma unroll
            for (int j = 0; j < 8; ++j) {
                float wk = (k==0)?wv[j].x:(k==1)?wv[j].y:(k==2)?wv[j].z:wv[j].w;
                acc[j] += bf2f(t[j]) * wk;
            }
        }
    }
    u16x8 o;
    #pragma unroll
    for (int j = 0; j < 8; ++j) {
        float s = acc[j] / (1.f + __expf(-acc[j]));
        o[j] = f2bf(s);
    }
    *(u16x8*)(xc + e0) = o;
}

// ---------------- f32 -> bf16 cast (weights), 8 elems/thread ----------------
__global__ __launch_bounds__(256) void k_cast_bf16(const float* __restrict__ src,
                                                   __hip_bfloat16* __restrict__ dst)
{
    size_t p = (size_t)blockIdx.x * 256 + threadIdx.x;
    const float4* s4 = (const float4*)src;
    float4 a = s4[p*2], b = s4[p*2 + 1];
    u16x8 o;
    o[0]=f2bf(a.x); o[1]=f2bf(a.y); o[2]=f2bf(a.z); o[3]=f2bf(a.w);
    o[4]=f2bf(b.x); o[5]=f2bf(b.y); o[6]=f2bf(b.z); o[7]=f2bf(b.w);
    ((u16x8*)dst)[p] = o;
}

// ---------------- bf16 NT GEMM: acc[m][n] = sum_k A[m][k] * W[n][k] ----------------
// Round-7: identical to round-6's verified pipeline, MINUS the XCD swizzle.
// Evidence: r0 (128², linear order) FETCH=227MB vs r6 (128², swizzle) FETCH=806MB —
// linear dispatch gives free neighbor-block B-panel sharing per XCD L2 (inputs are
// L3-fit, so T1 is net-negative here per m160).
// 128x128 tile, BK=32, 4 waves (2x2 of 64x64), 3-buffer depth-2 free-run pipeline,
// LDS = 3 x (A 8KB + B 8KB) = 48 KiB -> 3 blocks/CU (m97-style occupancy; m114
// cross-block MFMA||LDS||stage overlap).
// Packed-pair conflict-free LDS layout: global (m, kg: 8-elem k-group 0..3) stored
// at LDS row r=m>>1 (128 B rows), slot s = ((m&1)*4+kg) ^ (r&7). Wave read
// (fr=lane&15, qk=lane>>4): slot residues hit every bank-pair exactly 2x -> free
// (m136: 2-way is free). Stage: linear gload_lds dest (wave-uniform base+lane*16),
// per-lane pre-swizzled global source (rule #21). Verified r6: conflicts = 0.
// Ledger: prologue stages tiles 0,1 (8 outstanding/thread); top of tile t waits
// vmcnt(4) (retires tile t), stages tile t+2 into buf (t+2)%3 = (t-1)%3 (reads of
// that buf closed by the barrier). Last tile: vmcnt(0). T5 setprio around MFMAs.
// MODE 0: in_proj — stream 0: la = -clip(softplus(acc+dt_bias[n]),0.001,2) (f32)
//                   stream 1: v raw (bf16);  stream 2: sigmoid -> gate (bf16)
// MODE 1: out_proj — out[off] = acc + resid[off]  (f32)
template<int MODE>
__global__ __launch_bounds__(256, 3) void k_gemm(const __hip_bfloat16* __restrict__ Abf,
                                              const __hip_bfloat16* __restrict__ Wbf,
                                              int K,
                                              float* __restrict__ o0,
                                              __hip_bfloat16* __restrict__ o1,
                                              __hip_bfloat16* __restrict__ o2,
                                              const float* __restrict__ dt_bias,
                                              const float* __restrict__ resid,
                                              float* __restrict__ outp)
{
    // [buf 0..2][A=0/B=1][64 rows x 128 B = 8 KiB]
    __shared__ __attribute__((aligned(16))) char lds[3][2][8192];
    const __bf16* A = (const __bf16*)Abf;
    const __bf16* W = (const __bf16*)Wbf;
    const int tid  = threadIdx.x;
    const int wave = tid >> 6;
    const int lane = tid & 63;

    // NO XCD swizzle (round-7 change): linear dispatch order -> 64 consecutive
    // blocks share one B-panel (L2-resident) while streaming A.
    const int bx = blockIdx.x;
    const int by = blockIdx.y;

    const size_t m0 = (size_t)bx * 128;
    const size_t n0 = (size_t)by * 128;
    const int wm = (wave & 1) * 64;
    const int wn = (wave >> 1) * 64;

    v4f acc[4][4] = {};

    const int fr = lane & 15;             // fragment row within 16
    const int qk = lane >> 4;             // 8-elem k-group 0..3
    const int srL = lane >> 3;            // stage: row within 8-row lane slab
    const int ssL = lane & 7;             // stage: slot

    const int nt = K >> 5;                // BK=32

    // stage tile T (A or B, full 128 rows x 32 cols) into buf[T%3]; 2 issues/thread
    auto stage = [&](int T, int isB) {
        char* reg = &lds[T % 3][isB][0];
        const __bf16* gp = (isB ? W + n0 * (size_t)K : A + m0 * (size_t)K);
        #pragma unroll
        for (int is = 0; is < 2; ++is) {
            int r  = is*32 + wave*8 + srL;          // LDS row 0..63
            int u  = ssL ^ (r & 7);                 // unswizzled slot
            int m  = 2*r + (u >> 2);                // global row 0..127
            int kg = u & 3;
            const __bf16* src = gp + (size_t)m * K + (T << 5) + kg*8;
            async_copy16((void*)(reg + is*4096 + wave*1024), (const void*)src);
        }
    };
    // read 4 fragments (rows wbase + i*16 + fr, k-group qk)
    auto rd = [&](v8bf* f, const char* reg, int wbase) {
        #pragma unroll
        for (int i = 0; i < 4; ++i) {
            int m = wbase + i*16 + fr;
            int r = m >> 1;
            int s = (((m & 1) << 2) | qk) ^ (r & 7);
            f[i] = *(const v8bf*)(reg + r*128 + s*16);
        }
    };

    // prologue: tiles 0 and 1 -> 8 outstanding/thread
    stage(0, 0); stage(0, 1);
    stage(1, 0); stage(1, 1);

    for (int t = 0; t < nt; ++t) {
        if (t + 1 < nt) { asm volatile("s_waitcnt vmcnt(4)" ::: "memory"); }
        else            { asm volatile("s_waitcnt vmcnt(0)" ::: "memory"); }
        __builtin_amdgcn_s_barrier();      // tile t visible; reads of buf (t-1)%3 closed
        __builtin_amdgcn_sched_barrier(0);

        const char* Ab = &lds[t % 3][0][0];
        const char* Bb = &lds[t % 3][1][0];

        if (t + 2 < nt) { stage(t + 2, 0); stage(t + 2, 1); }

        v8bf fa[4], fb[4];
        rd(fa, Ab, wm);
        rd(fb, Bb, wn);

        __builtin_amdgcn_s_setprio(1);
        #pragma unroll
        for (int i = 0; i < 4; ++i)
            #pragma unroll
            for (int j = 0; j < 4; ++j)
                acc[i][j] = __builtin_amdgcn_mfma_f32_16x16x32_bf16(fa[i], fb[j], acc[i][j], 0, 0, 0);
        __builtin_amdgcn_s_setprio(0);
    }

    // epilogue: C/D layout col=lane&15, row=(lane>>4)*4+r  (m89-verified)
    const int col = lane & 15;
    const int rb  = (lane >> 4) * 4;
    if (MODE == 0) {
        const int stream = by >> 4;                 // 2048/128 = 16 blocks/stream
        const size_t nb = n0 - (size_t)stream * D_;
        #pragma unroll
        for (int i = 0; i < 4; ++i)
            #pragma unroll
            for (int j = 0; j < 4; ++j) {
                size_t nIdx = nb + wn + j*16 + col;
                #pragma unroll
                for (int r = 0; r < 4; ++r) {
                    size_t m = m0 + wm + i*16 + rb + r;
                    size_t off = m * (size_t)D_ + nIdx;
                    float v = acc[i][j][r];
                    if (stream == 0) {
                        float xx = v + dt_bias[nIdx];
                        float e  = __expf(-fabsf(xx));
                        float sp = fmaxf(xx, 0.f) + __logf(1.f + e);
                        float dt = fminf(fmaxf(sp, 0.001f), 2.0f);
                        o0[off] = -dt;                                    // log_alpha
                    } else if (stream == 1) {
                        o1[off] = __float2bfloat16(v);                    // raw v
                    } else {
                        o2[off] = __float2bfloat16(1.f/(1.f+__expf(-v))); // gate
                    }
                }
            }
    } else {
        #pragma unroll
        for (int i = 0; i < 4; ++i)
            #pragma unroll
            for (int j = 0; j < 4; ++j)
                #pragma unroll
                for (int r = 0; r < 4; ++r) {
                    size_t m = m0 + wm + i*16 + rb + r;
                    size_t off = m * (size_t)D_ + n0 + wn + j*16 + col;
                    outp[off] = acc[i][j][r] + resid[off];
                }
    }
}

// ---------------- scan phase 1: RoPE*dt fused; writes bd, bo, nc (f32), expL (bf16) ----
// nc[off]  = chunk-local scan output (pre-carry), f32.
// expL[off]= exp(L_t), bf16 (only scales the decaying carry term -> 0.4% rel ok).
__global__ __launch_bounds__(256) void k_scan1(const float* __restrict__ la,
                                               const __hip_bfloat16* __restrict__ v,
                                               float* __restrict__ bd, float* __restrict__ bo,
                                               float* __restrict__ nc,
                                               __hip_bfloat16* __restrict__ expL)
{
    int idx = blockIdx.x * 256 + threadIdx.x;   // B*NC*D = 65536
    int d = idx & (D_-1);
    int c = (idx >> 11) & (NC_-1);
    int b = idx >> 15;
    int i = d & 63;
    const bool firstHalf = (d & 64) == 0;
    float inv = __expf((float)i * (-9.210340371976184f / 64.f)); // 10000^(-i/64)
    int n0 = c * CHUNK_;
    // incremental rotation: (cs,sn) = (cos,sin)(n*inv), step by inv
    float cs = cosf((float)n0 * inv), sn = sinf((float)n0 * inv);
    float ca = cosf(inv), sa = sinf(inv);
    size_t row0 = (size_t)b * N_ + (size_t)c * CHUNK_;
    float S = 0.f, Lp = 0.f, out = 0.f;
    #pragma unroll 8
    for (int t = 0; t < CHUNK_; ++t) {
        size_t off = (row0 + t) * (size_t)D_ + d;
        float a  = la[off];
        float vo = __bfloat162float(v[off]);
        float vp = __bfloat162float(v[firstHalf ? off + 64 : off - 64]);
        float dt = -a;
        float vin = (firstHalf ? (vo*cs - vp*sn) : (vp*sn + vo*cs)) * dt;
        S += a;
        float L = fmaxf(S, -20.f);           // clip(cumsum,-20,0): upper never binds
        out = __expf(L - Lp) * out + vin;
        Lp = L;
        nc[off]   = out;
        expL[off] = __float2bfloat16(__expf(L));
        float csn = cs*ca - sn*sa;           // advance angle by inv
        sn = sn*ca + cs*sa;
        cs = csn;
    }
    bd[idx] = Lp;
    bo[idx] = out;
}

// ---------------- scan phase 2: cross-chunk combine -> carries ----------------
__global__ __launch_bounds__(256) void k_scan2(const float* __restrict__ bd,
                                               const float* __restrict__ bo,
                                               float* __restrict__ carries)
{
    int idx = blockIdx.x * 256 + threadIdx.x;   // B*D = 4096
    int d = idx & (D_-1);
    int b = idx >> 11;
    float bd0 = bd[(size_t)(b*NC_)*D_ + d];     // stab = cd[0] = bd[0] (>= -20)
    float cd = 0.f, acc = 0.f;
    #pragma unroll
    for (int c = 0; c < NC_; ++c) {
        size_t o = (size_t)(b*NC_ + c)*D_ + d;
        cd = fmaxf(cd + bd[o], -80.f);          // clip(cumsum(bd),-80,0)
        float ncd = fmaxf(cd - bd0, -20.f);     // clip(cd-stab,-20,0)
        carries[o] = acc * __expf(ncd);         // sum of seeds STRICTLY BEFORE c
        acc += bo[o] * __expf(-ncd);
    }
}

// ---------------- scan fixup (replaces serial scan3): elementwise, in-place over expL ----
// state[off] = bf16( nc[off] + carr[b,c,d] * expL[off] );  stex holds expL in, state out.
__global__ __launch_bounds__(256) void k_scanfix(const float* __restrict__ nc,
                                                 __hip_bfloat16* __restrict__ stex,
                                                 const float* __restrict__ carr)
{
    size_t idx = (size_t)blockIdx.x * 256 + threadIdx.x;   // over M*D/8
    size_t e0 = idx * 8;
    int d0 = (int)(e0 & (D_-1));
    int token = (int)(e0 >> 11);
    int b = token >> 12;                 // N_=4096
    int c = (token & (N_-1)) >> 8;       // CHUNK_=256
    const float* cp = carr + ((size_t)(b*NC_ + c)) * D_ + d0;
    u16x8 el = ((const u16x8*)stex)[idx];
    const float4* n4 = (const float4*)(nc + e0);
    float4 na = n4[0], nb = n4[1];
    const float4* c4 = (const float4*)cp;
    float4 ca = c4[0], cb = c4[1];
    float nv[8] = { na.x, na.y, na.z, na.w, nb.x, nb.y, nb.z, nb.w };
    float cv[8] = { ca.x, ca.y, ca.z, ca.w, cb.x, cb.y, cb.z, cb.w };
    u16x8 o;
    #pragma unroll
    for (int j = 0; j < 8; ++j)
        o[j] = f2bf(nv[j] + cv[j] * bf2f(el[j]));
    ((u16x8*)stex)[idx] = o;
}

// ---------------- head_mix (generic 16x16) * gate -> y (bf16) ----------------
__global__ __launch_bounds__(256) void k_headmix_gate(const __hip_bfloat16* __restrict__ state,
                                                      const __hip_bfloat16* __restrict__ gate,
                                                      const float* __restrict__ hm,
                                                      __hip_bfloat16* __restrict__ y)
{
    __shared__ float lf[D_];
    __shared__ float lhm[H_*H_];
    const int row = blockIdx.x;
    const size_t base = (size_t)row * D_;
    u16x8 s8 = ((const u16x8*)(state + base))[threadIdx.x];
    #pragma unroll
    for (int j = 0; j < 8; ++j) lf[threadIdx.x*8 + j] = bf2f(s8[j]);
    if (threadIdx.x < H_*H_) lhm[threadIdx.x] = hm[threadIdx.x];
    __syncthreads();
    #pragma unroll
    for (int k = 0; k < 8; ++k) {
        int o = threadIdx.x + k*256;
        int m  = o >> 7;
        int dh = o & 127;
        float s = 0.f;
        #pragma unroll
        for (int h = 0; h < H_; ++h) s += lf[h*DH_ + dh] * lhm[h*H_ + m];
        float g = __bfloat162float(gate[base + o]);
        y[base + o] = __float2bfloat16(s * g);
    }
}

extern "C" void kernel_launch(void* const* d_in, const int* in_sizes, int n_in,
                              void* d_out, int out_size, void* d_ws, size_t ws_size,
                              hipStream_t stream)
{
    const float* x          = (const float*)d_in[0];
    const float* norm_scale = (const float*)d_in[1];
    const float* conv_w     = (const float*)d_in[2];
    const float* conv_b     = (const float*)d_in[3];
    const float* in_proj_w  = (const float*)d_in[4];
    const float* dt_bias    = (const float*)d_in[5];
    const float* head_mix   = (const float*)d_in[6];
    const float* out_proj_w = (const float*)d_in[7];
    float* out = (float*)d_out;

    // Workspace layout — total 176,947,200 B.
    char* ws = (char*)d_ws;
    float*          la   = (float*)ws;                               // 67,108,864 B (log_alpha, f32)
    __hip_bfloat16* xn   = (__hip_bfloat16*)(ws + 67108864);         // 33,554,432 B; -> w1 after conv
    __hip_bfloat16* xc   = (__hip_bfloat16*)(ws + 100663296);        // 33,554,432 B; -> y after scanfix
    __hip_bfloat16* gate = (__hip_bfloat16*)(ws + 134217728);        // 33,554,432 B
    __hip_bfloat16* w2   = (__hip_bfloat16*)(ws + 167772160);        //  8,388,608 B
    float*          bd   = (float*)(ws + 176160768);                 //    262,144 B
    float*          bo   = (float*)(ws + 176422912);                 //    262,144 B
    float*          carr = (float*)(ws + 176685056);                 //    262,144 B
    __hip_bfloat16* w1   = xn;   // xn dead after conv
    // nc (f32, M*D = 67 MB) spans xn+xc — both dead during the scan (w1 consumed by
    // GEMM1, xc consumed by GEMM1); y (=xc) is written by headmix AFTER nc is dead.
    float*          nc   = (float*)(ws + 67108864);
    __hip_bfloat16* y    = xc;
    // d_out scratch: v (bf16, first half); stex (second half) holds expL then state
    // (scanfix is elementwise in-place), all dead before GEMM2 writes the final out.
    __hip_bfloat16* v     = (__hip_bfloat16*)d_out;
    __hip_bfloat16* stex  = (__hip_bfloat16*)((char*)d_out + 33554432);

    k_rmsnorm<<<M_, 256, 0, stream>>>(x, norm_scale, xn);
    k_conv_silu<<<(M_*(size_t)D_)/8/256, 256, 0, stream>>>(xn, conv_w, conv_b, xc);
    k_cast_bf16<<<6144, 256, 0, stream>>>(in_proj_w, w1);
    k_cast_bf16<<<2048, 256, 0, stream>>>(out_proj_w, w2);
    k_gemm<0><<<dim3(M_/128, F3D/128), 256, 0, stream>>>(xc, w1, D_, la, v, gate, dt_bias, nullptr, nullptr);
    k_scan1<<<(B_*NC_*D_)/256, 256, 0, stream>>>(la, v, bd, bo, nc, stex);
    k_scan2<<<(B_*D_)/256, 256, 0, stream>>>(bd, bo, carr);
    k_scanfix<<<(M_*(size_t)D_)/8/256, 256, 0, stream>>>(nc, stex, carr);
    k_headmix_gate<<<M_, 256, 0, stream>>>(stex, gate, head_mix, y);
    k_gemm<1><<<dim3(M_/128, D_/128), 256, 0, stream>>>(y, w2, D_, nullptr, nullptr, nullptr, nullptr, x, out);
}

// Round 9
// 637.124 us; speedup vs baseline: 1.1814x; 1.0804x over previous
//
#include <hip/hip_runtime.h>
#include <hip/hip_bf16.h>
#include <math.h>

// Problem constants (fixed by setup_inputs)
#define B_ 2
#define N_ 4096
#define D_ 2048
#define H_ 16
#define DH_ 128
#define CHUNK_ 256
#define NC_ 16
#define M_ (B_*N_)          // 8192 tokens
#define F3D (3*D_)          // 6144

typedef __bf16 v8bf __attribute__((ext_vector_type(8)));
typedef float  v4f  __attribute__((ext_vector_type(4)));
typedef unsigned short u16x8 __attribute__((ext_vector_type(8)));

__device__ __forceinline__ float bf2f(unsigned short u) {
    union { unsigned int i; float f; } c; c.i = ((unsigned int)u) << 16; return c.f;
}
__device__ __forceinline__ unsigned short f2bf(float f) {
    __hip_bfloat16 h = __float2bfloat16(f);
    return *(unsigned short*)&h;
}

// Measured-good form ONLY: offset imm = 0 (learn_hip m03/m97). r8's non-zero
// offset imm produced NaN — semantics of that operand are unverified on gfx950.
__device__ __forceinline__ void async_copy16(void* lds, const void* g) {
    __builtin_amdgcn_global_load_lds(
        (const __attribute__((address_space(1))) unsigned int*)g,
        (__attribute__((address_space(3))) unsigned int*)lds,
        16, 0, 0);
}

// ---------------- RMSNorm: x (f32) -> xn (bf16), 8 elems/thread ----------------
__global__ __launch_bounds__(256) void k_rmsnorm(const float* __restrict__ x,
                                                 const float* __restrict__ scale,
                                                 __hip_bfloat16* __restrict__ xn)
{
    __shared__ float red[4];
    const int row = blockIdx.x;
    const float4* x4 = (const float4*)(x + (size_t)row * D_);
    float4 a = x4[threadIdx.x*2];
    float4 b = x4[threadIdx.x*2 + 1];
    float ss = a.x*a.x + a.y*a.y + a.z*a.z + a.w*a.w
             + b.x*b.x + b.y*b.y + b.z*b.z + b.w*b.w;
    #pragma unroll
    for (int off = 32; off > 0; off >>= 1) ss += __shfl_down(ss, off, 64);
    if ((threadIdx.x & 63) == 0) red[threadIdx.x >> 6] = ss;
    __syncthreads();
    float tot = red[0] + red[1] + red[2] + red[3];
    float r = rsqrtf(tot / (float)D_ + 1e-6f);
    const float4* s4 = (const float4*)scale;
    float4 sa = s4[threadIdx.x*2];
    float4 sb = s4[threadIdx.x*2 + 1];
    float v[8] = { sa.x*a.x, sa.y*a.y, sa.z*a.z, sa.w*a.w,
                   sb.x*b.x, sb.y*b.y, sb.z*b.z, sb.w*b.w };
    u16x8 o;
    #pragma unroll
    for (int j = 0; j < 8; ++j) {
        float t = fminf(fmaxf(v[j]*r, -60000.f), 60000.f);
        o[j] = f2bf(t);
    }
    ((u16x8*)(xn + (size_t)row * D_))[threadIdx.x] = o;
}

// ---------------- depthwise causal conv (K=4) + SiLU, 8 elems/thread ----------------
__global__ __launch_bounds__(256) void k_conv_silu(const __hip_bfloat16* __restrict__ xn,
                                                   const float* __restrict__ w,
                                                   const float* __restrict__ bias,
                                                   __hip_bfloat16* __restrict__ xc)
{
    size_t p = (size_t)blockIdx.x * 256 + threadIdx.x;  // over M*D/8
    size_t e0 = p * 8;
    int d0 = (int)(e0 & (D_-1));
    int n  = (int)((e0 >> 11) & (N_-1));
    const float4* w4 = (const float4*)w;               // w4[d] = weights of channel d
    float acc[8];
    const float4* b4 = (const float4*)(bias + d0);
    float4 ba = b4[0], bb = b4[1];
    acc[0]=ba.x; acc[1]=ba.y; acc[2]=ba.z; acc[3]=ba.w;
    acc[4]=bb.x; acc[5]=bb.y; acc[6]=bb.z; acc[7]=bb.w;
    float4 wv[8];
    #pragma unroll
    for (int j = 0; j < 8; ++j) wv[j] = w4[d0 + j];
    #pragma unroll
    for (int k = 0; k < 4; ++k) {
        int nn = n - 3 + k;
        if (nn >= 0) {
            u16x8 t = *(const u16x8*)(xn + e0 - (size_t)(3-k)*D_);
            #pragma unroll
            for (int j = 0; j < 8; ++j) {
                float wk = (k==0)?wv[j].x:(k==1)?wv[j].y:(k==2)?wv[j].z:wv[j].w;
                acc[j] += bf2f(t[j]) * wk;
            }
        }
    }
    u16x8 o;
    #pragma unroll
    for (int j = 0; j < 8; ++j) {
        float s = acc[j] / (1.f + __expf(-acc[j]));
        o[j] = f2bf(s);
    }
    *(u16x8*)(xc + e0) = o;
}

// ---------------- f32 -> bf16 cast, BOTH weights in one launch ----------------
#define W1_VECS 1572864   // 6144*2048/8 (block-uniform branch: 6144 blocks exactly)
__global__ __launch_bounds__(256) void k_cast2(const float* __restrict__ s1,
                                               __hip_bfloat16* __restrict__ d1,
                                               const float* __restrict__ s2,
                                               __hip_bfloat16* __restrict__ d2)
{
    size_t p = (size_t)blockIdx.x * 256 + threadIdx.x;
    const float* src; __hip_bfloat16* dst; size_t q;
    if (p < W1_VECS) { src = s1; dst = d1; q = p; }
    else             { src = s2; dst = d2; q = p - W1_VECS; }
    const float4* s4 = (const float4*)src;
    float4 a = s4[q*2], b = s4[q*2 + 1];
    u16x8 o;
    o[0]=f2bf(a.x); o[1]=f2bf(a.y); o[2]=f2bf(a.z); o[3]=f2bf(a.w);
    o[4]=f2bf(b.x); o[5]=f2bf(b.y); o[6]=f2bf(b.z); o[7]=f2bf(b.w);
    ((u16x8*)dst)[q] = o;
}

// ---------------- bf16 NT GEMM: acc[m][n] = sum_k A[m][k] * W[n][k], K=2048 ----------
// Round-9 = round-8 with staging reverted to the MEASURED global_load_lds form
// (offset imm = 0; full per-lane addresses; pointers advanced +32 elems per STAGE).
// m97-style 2-buffer drain pipeline, addressing hoisted out of the K-loop:
// 128x128 tile, BK=32, 4 waves (2x2 of 64x64), LDS = 2 x (A 8KB + B 8KB) = 32 KiB
// -> 4 blocks/CU (__launch_bounds__(256,4)): GEMM1 grid 3072 = 3 even rounds,
// GEMM2 grid 1024 = 1 round. Loop unrolled by 2 (tile e->buf0, e+1->buf1): buffer
// selects static; ds_read uses ONE per-lane base + compile-time imm offsets.
// Per tile: { vmcnt(0); barrier; stage(next, 4x gload_lds); 8x ds_read; 16 MFMA }.
// WAR: stage targets the buffer whose reads were closed by this tile's barrier
// (each wave's ds_reads complete before its MFMAs, which precede the barrier).
// Conflict-free packed-pair swizzle (r6/r7-verified, SQ_LDS_BANK_CONFLICT=0):
// global (m,kg) at LDS row r=m>>1, slot ((m&1)*4+kg)^(r&7); read side inverse.
// No XCD swizzle (r7: linear order keeps FETCH ~275MB). T5 setprio on MFMAs.
// MODE 0: in_proj — stream 0: la = -clip(softplus(acc+dt_bias),0.001,2) (bf16)
//                   stream 1: v raw (bf16);  stream 2: sigmoid -> gate (bf16)
// MODE 1: out_proj — out[off] = acc + resid[off]  (f32)
template<int MODE>
__global__ __launch_bounds__(256, 4) void k_gemm(const __hip_bfloat16* __restrict__ Abf,
                                              const __hip_bfloat16* __restrict__ Wbf,
                                              __hip_bfloat16* __restrict__ o0,
                                              __hip_bfloat16* __restrict__ o1,
                                              __hip_bfloat16* __restrict__ o2,
                                              const float* __restrict__ dt_bias,
                                              const float* __restrict__ resid,
                                              float* __restrict__ outp)
{
    // [buf 0/1][A=0/B=1][64 rows x 128 B = 8 KiB]
    __shared__ __attribute__((aligned(16))) char lds[2][2][8192];
    const __bf16* A = (const __bf16*)Abf;
    const __bf16* W = (const __bf16*)Wbf;
    const int tid  = threadIdx.x;
    const int wave = tid >> 6;
    const int lane = tid & 63;
    const size_t m0 = (size_t)blockIdx.x * 128;
    const size_t n0 = (size_t)blockIdx.y * 128;
    const int wm = (wave & 1) * 64;
    const int wn = (wave >> 1) * 64;

    v4f acc[4][4] = {};

    // ---- read-side per-lane bases (swizzled); i-th fragment at +i*1024 (imm) ----
    const int fr = lane & 15;
    const int qk = lane >> 4;
    int mA = wm + fr, rA = mA >> 1;
    int mB = wn + fr, rB = mB >> 1;
    const char* vA = &lds[0][0][0] + rA*128 + (((((mA&1)<<2)|qk) ^ (rA&7)) << 4);
    const char* vB = &lds[0][1][0] + rB*128 + (((((mB&1)<<2)|qk) ^ (rB&7)) << 4);

    // ---- stage-side: 4 inductive per-thread global srcs; wave-uniform LDS dests ----
    const int srL = lane >> 3, ssL = lane & 7;
    const __bf16 *sA0, *sA1, *sB0, *sB1;
    {
        int r0 = wave*8 + srL,      u0 = ssL ^ (r0 & 7);
        int r1 = 32 + wave*8 + srL, u1 = ssL ^ (r1 & 7);
        int ma0 = 2*r0 + (u0 >> 2), kg0 = u0 & 3;
        int ma1 = 2*r1 + (u1 >> 2), kg1 = u1 & 3;
        sA0 = A + (m0 + ma0)*(size_t)2048 + kg0*8;
        sA1 = A + (m0 + ma1)*(size_t)2048 + kg1*8;
        sB0 = W + (n0 + ma0)*(size_t)2048 + kg0*8;
        sB1 = W + (n0 + ma1)*(size_t)2048 + kg1*8;
    }
    char* dA0 = &lds[0][0][0] + wave*1024;          // + is*4096; buf1 = +16384
    char* dB0 = &lds[0][1][0] + wave*1024;

    // stages the tile the pointers currently aim at, then advances them one tile
    #define STAGE(BUF) do { \
        async_copy16(dA0 + (BUF)*16384,        sA0); \
        async_copy16(dA0 + (BUF)*16384 + 4096, sA1); \
        async_copy16(dB0 + (BUF)*16384,        sB0); \
        async_copy16(dB0 + (BUF)*16384 + 4096, sB1); \
        sA0 += 32; sA1 += 32; sB0 += 32; sB1 += 32; } while(0)

    STAGE(0);                                       // prologue: tile 0 -> buf0

    for (int i2 = 0; i2 < 32; ++i2) {
        // ---- tile e = 2*i2 (buf0) ----
        asm volatile("s_waitcnt vmcnt(0)" ::: "memory");
        __builtin_amdgcn_s_barrier();
        __builtin_amdgcn_sched_barrier(0);
        STAGE(1);                                   // tile e+1 -> buf1
        {
            v8bf fa[4], fb[4];
            #pragma unroll
            for (int i = 0; i < 4; ++i) fa[i] = *(const v8bf*)(vA + i*1024);
            #pragma unroll
            for (int j = 0; j < 4; ++j) fb[j] = *(const v8bf*)(vB + j*1024);
            __builtin_amdgcn_s_setprio(1);
            #pragma unroll
            for (int i = 0; i < 4; ++i)
                #pragma unroll
                for (int j = 0; j < 4; ++j)
                    acc[i][j] = __builtin_amdgcn_mfma_f32_16x16x32_bf16(fa[i], fb[j], acc[i][j], 0, 0, 0);
            __builtin_amdgcn_s_setprio(0);
        }
        // ---- tile o = e+1 (buf1) ----
        asm volatile("s_waitcnt vmcnt(0)" ::: "memory");
        __builtin_amdgcn_s_barrier();
        __builtin_amdgcn_sched_barrier(0);
        if (i2 + 1 < 32) STAGE(0);                  // tile e+2 -> buf0
        {
            v8bf fa[4], fb[4];
            #pragma unroll
            for (int i = 0; i < 4; ++i) fa[i] = *(const v8bf*)(vA + 16384 + i*1024);
            #pragma unroll
            for (int j = 0; j < 4; ++j) fb[j] = *(const v8bf*)(vB + 16384 + j*1024);
            __builtin_amdgcn_s_setprio(1);
            #pragma unroll
            for (int i = 0; i < 4; ++i)
                #pragma unroll
                for (int j = 0; j < 4; ++j)
                    acc[i][j] = __builtin_amdgcn_mfma_f32_16x16x32_bf16(fa[i], fb[j], acc[i][j], 0, 0, 0);
            __builtin_amdgcn_s_setprio(0);
        }
    }
    #undef STAGE

    // epilogue: C/D layout col=lane&15, row=(lane>>4)*4+r  (m89-verified)
    const int col = lane & 15;
    const int rb  = (lane >> 4) * 4;
    if (MODE == 0) {
        const int stream = blockIdx.y >> 4;         // 2048/128 = 16 blocks/stream
        const size_t nb = n0 - (size_t)stream * D_;
        #pragma unroll
        for (int i = 0; i < 4; ++i)
            #pragma unroll
            for (int j = 0; j < 4; ++j) {
                size_t nIdx = nb + wn + j*16 + col;
                #pragma unroll
                for (int r = 0; r < 4; ++r) {
                    size_t m = m0 + wm + i*16 + rb + r;
                    size_t off = m * (size_t)D_ + nIdx;
                    float v = acc[i][j][r];
                    if (stream == 0) {
                        float xx = v + dt_bias[nIdx];
                        float e  = __expf(-fabsf(xx));
                        float sp = fmaxf(xx, 0.f) + __logf(1.f + e);
                        float dt = fminf(fmaxf(sp, 0.001f), 2.0f);
                        o0[off] = __float2bfloat16(-dt);                  // la (bf16)
                    } else if (stream == 1) {
                        o1[off] = __float2bfloat16(v);                    // raw v
                    } else {
                        o2[off] = __float2bfloat16(1.f/(1.f+__expf(-v))); // gate
                    }
                }
            }
    } else {
        #pragma unroll
        for (int i = 0; i < 4; ++i)
            #pragma unroll
            for (int j = 0; j < 4; ++j)
                #pragma unroll
                for (int r = 0; r < 4; ++r) {
                    size_t m = m0 + wm + i*16 + rb + r;
                    size_t off = m * (size_t)D_ + n0 + wn + j*16 + col;
                    outp[off] = acc[i][j][r] + resid[off];
                }
    }
}

// ---------------- scan phase 1: RoPE*dt fused; writes bd, bo, nc (f32), expL (bf16) ----
// la is bf16 (0.2% rel on dt -> within tolerance).
__global__ __launch_bounds__(256) void k_scan1(const __hip_bfloat16* __restrict__ la,
                                               const __hip_bfloat16* __restrict__ v,
                                               float* __restrict__ bd, float* __restrict__ bo,
                                               float* __restrict__ nc,
                                               __hip_bfloat16* __restrict__ expL)
{
    int idx = blockIdx.x * 256 + threadIdx.x;   // B*NC*D = 65536
    int d = idx & (D_-1);
    int c = (idx >> 11) & (NC_-1);
    int b = idx >> 15;
    int i = d & 63;
    const bool firstHalf = (d & 64) == 0;
    float inv = __expf((float)i * (-9.210340371976184f / 64.f)); // 10000^(-i/64)
    int n0 = c * CHUNK_;
    float cs = cosf((float)n0 * inv), sn = sinf((float)n0 * inv);
    float ca = cosf(inv), sa = sinf(inv);
    size_t row0 = (size_t)b * N_ + (size_t)c * CHUNK_;
    float S = 0.f, Lp = 0.f, out = 0.f;
    #pragma unroll 8
    for (int t = 0; t < CHUNK_; ++t) {
        size_t off = (row0 + t) * (size_t)D_ + d;
        float a  = __bfloat162float(la[off]);
        float vo = __bfloat162float(v[off]);
        float vp = __bfloat162float(v[firstHalf ? off + 64 : off - 64]);
        float dt = -a;
        float vin = (firstHalf ? (vo*cs - vp*sn) : (vp*sn + vo*cs)) * dt;
        S += a;
        float L = fmaxf(S, -20.f);           // clip(cumsum,-20,0): upper never binds
        out = __expf(L - Lp) * out + vin;
        Lp = L;
        nc[off]   = out;
        expL[off] = __float2bfloat16(__expf(L));
        float csn = cs*ca - sn*sa;           // advance angle by inv
        sn = sn*ca + cs*sa;
        cs = csn;
    }
    bd[idx] = Lp;
    bo[idx] = out;
}

// ---------------- scan phase 2: cross-chunk combine -> carries ----------------
__global__ __launch_bounds__(256) void k_scan2(const float* __restrict__ bd,
                                               const float* __restrict__ bo,
                                               float* __restrict__ carries)
{
    int idx = blockIdx.x * 256 + threadIdx.x;   // B*D = 4096
    int d = idx & (D_-1);
    int b = idx >> 11;
    float bd0 = bd[(size_t)(b*NC_)*D_ + d];     // stab = cd[0] = bd[0] (>= -20)
    float cd = 0.f, acc = 0.f;
    #pragma unroll
    for (int c = 0; c < NC_; ++c) {
        size_t o = (size_t)(b*NC_ + c)*D_ + d;
        cd = fmaxf(cd + bd[o], -80.f);          // clip(cumsum(bd),-80,0)
        float ncd = fmaxf(cd - bd0, -20.f);     // clip(cd-stab,-20,0)
        carries[o] = acc * __expf(ncd);         // sum of seeds STRICTLY BEFORE c
        acc += bo[o] * __expf(-ncd);
    }
}

// ---------------- fused: state = nc + carr*expL, head_mix, * gate -> y (bf16) ----------
__global__ __launch_bounds__(256) void k_hmix(const float* __restrict__ nc,
                                              const __hip_bfloat16* __restrict__ expL,
                                              const float* __restrict__ carr,
                                              const __hip_bfloat16* __restrict__ gate,
                                              const float* __restrict__ hm,
                                              __hip_bfloat16* __restrict__ y)
{
    __shared__ float lf[D_];
    __shared__ float lhm[H_*H_];
    const int row = blockIdx.x;
    const size_t base = (size_t)row * D_;
    const int b = row >> 12;                 // N_=4096 rows per batch
    const int c = (row >> 8) & (NC_-1);      // chunk of this token
    const float* cp = carr + ((size_t)(b*NC_ + c)) * D_ + threadIdx.x*8;
    u16x8 el = ((const u16x8*)(expL + base))[threadIdx.x];
    const float4* n4 = (const float4*)(nc + base + threadIdx.x*8);
    float4 na = n4[0], nb = n4[1];
    const float4* c4 = (const float4*)cp;
    float4 ca = c4[0], cb = c4[1];
    float nv[8] = { na.x, na.y, na.z, na.w, nb.x, nb.y, nb.z, nb.w };
    float cv[8] = { ca.x, ca.y, ca.z, ca.w, cb.x, cb.y, cb.z, cb.w };
    #pragma unroll
    for (int j = 0; j < 8; ++j)
        lf[threadIdx.x*8 + j] = nv[j] + cv[j] * bf2f(el[j]);
    lhm[threadIdx.x] = hm[threadIdx.x];      // H*H = 256 = blockDim
    __syncthreads();
    #pragma unroll
    for (int k = 0; k < 8; ++k) {
        int o = threadIdx.x + k*256;
        int m  = o >> 7;
        int dh = o & 127;
        float s = 0.f;
        #pragma unroll
        for (int h = 0; h < H_; ++h) s += lf[h*DH_ + dh] * lhm[h*H_ + m];
        float g = __bfloat162float(gate[base + o]);
        y[base + o] = __float2bfloat16(s * g);
    }
}

extern "C" void kernel_launch(void* const* d_in, const int* in_sizes, int n_in,
                              void* d_out, int out_size, void* d_ws, size_t ws_size,
                              hipStream_t stream)
{
    const float* x          = (const float*)d_in[0];
    const float* norm_scale = (const float*)d_in[1];
    const float* conv_w     = (const float*)d_in[2];
    const float* conv_b     = (const float*)d_in[3];
    const float* in_proj_w  = (const float*)d_in[4];
    const float* dt_bias    = (const float*)d_in[5];
    const float* head_mix   = (const float*)d_in[6];
    const float* out_proj_w = (const float*)d_in[7];
    float* out = (float*)d_out;

    // Workspace layout — total 176,947,200 B.
    char* ws = (char*)d_ws;
    __hip_bfloat16* la   = (__hip_bfloat16*)ws;                      // 33,554,432 B (bf16); -> y after scan1
    __hip_bfloat16* xn   = (__hip_bfloat16*)(ws + 67108864);         // 33,554,432 B; -> w1 after conv
    __hip_bfloat16* xc   = (__hip_bfloat16*)(ws + 100663296);        // 33,554,432 B
    __hip_bfloat16* gate = (__hip_bfloat16*)(ws + 134217728);        // 33,554,432 B
    __hip_bfloat16* w2   = (__hip_bfloat16*)(ws + 167772160);        //  8,388,608 B
    float*          bd   = (float*)(ws + 176160768);                 //    262,144 B
    float*          bo   = (float*)(ws + 176422912);                 //    262,144 B
    float*          carr = (float*)(ws + 176685056);                 //    262,144 B
    __hip_bfloat16* w1   = xn;   // xn dead after conv
    // nc (f32, M*D = 67MB) spans xn+xc — both consumed by GEMM1 before scan1 writes.
    float*          nc   = (float*)(ws + 67108864);
    // y lives in the la region (la dead after scan1; xc would race nc in k_hmix).
    __hip_bfloat16* y    = (__hip_bfloat16*)ws;
    // d_out scratch: v (bf16, first half); stex (second half) = expL, read by
    // k_hmix; all dead before GEMM2 writes the final f32 output.
    __hip_bfloat16* v     = (__hip_bfloat16*)d_out;
    __hip_bfloat16* stex  = (__hip_bfloat16*)((char*)d_out + 33554432);

    k_rmsnorm<<<M_, 256, 0, stream>>>(x, norm_scale, xn);
    k_conv_silu<<<(M_*(size_t)D_)/8/256, 256, 0, stream>>>(xn, conv_w, conv_b, xc);
    k_cast2<<<8192, 256, 0, stream>>>(in_proj_w, w1, out_proj_w, w2);
    k_gemm<0><<<dim3(M_/128, F3D/128), 256, 0, stream>>>(xc, w1, la, v, gate, dt_bias, nullptr, nullptr);
    k_scan1<<<(B_*NC_*D_)/256, 256, 0, stream>>>(la, v, bd, bo, nc, stex);
    k_scan2<<<(B_*D_)/256, 256, 0, stream>>>(bd, bo, carr);
    k_hmix<<<M_, 256, 0, stream>>>(nc, stex, carr, gate, head_mix, y);
    k_gemm<1><<<dim3(M_/128, D_/128), 256, 0, stream>>>(y, w2, nullptr, nullptr, nullptr, nullptr, x, out);
}